// Round 2
// baseline (298.185 us; speedup 1.0000x reference)
//
#include <hip/hip_runtime.h>

#define NQ 1024
#define NO 2048
#define LAT 128
#define HD 32
#define CHUNK 56
#define LOG2E 1.4426950408889634f
#define NEG_BIG -3.0e38f
#define PART_STRIDE 136   // 4 m + 4 lsum + 128 acc (floats per (slot,q))

// ---------------------------------------------------------------------------
// value path: h_obs <- LayerNorm(h_obs) @ Wv + bv   (in place; d_in restored
// by the harness before every launch, so mutating the input is safe)
// ---------------------------------------------------------------------------
__global__ __launch_bounds__(128) void gano_value(
    const float* __restrict__ ln_g,
    const float* __restrict__ ln_b,
    const float* __restrict__ Wv,
    const float* __restrict__ bv,
    float* __restrict__ h)
{
    __shared__ float hn[LAT];
    __shared__ float red[4];
    const int t = threadIdx.x;
    const int o = blockIdx.x;
    const float x = h[(size_t)o*LAT + t];
    float s1 = x, s2 = x*x;
#pragma unroll
    for (int off = 32; off >= 1; off >>= 1) {
        s1 += __shfl_xor(s1, off);
        s2 += __shfl_xor(s2, off);
    }
    if ((t & 63) == 0) { red[(t>>6)*2] = s1; red[(t>>6)*2+1] = s2; }
    __syncthreads();
    const float S1 = red[0] + red[2];
    const float S2 = red[1] + red[3];
    const float mean = S1 * (1.0f/LAT);
    const float var  = S2 * (1.0f/LAT) - mean*mean;
    const float rstd = rsqrtf(var + 1e-5f);
    hn[t] = (x - mean) * rstd * ln_g[t] + ln_b[t];
    __syncthreads();
    float acc = bv[t];
#pragma unroll 4
    for (int kk = 0; kk < LAT; ++kk)
        acc = fmaf(hn[kk], Wv[kk*LAT + t], acc);
    h[(size_t)o*LAT + t] = acc;   // each element read only by its own thread
}

// ---------------------------------------------------------------------------
// main: 4 threads per query (thread k owns head k = dims [32k,32k+32)).
// preact factorization: preact = c_q[dim] + d_o[dim] + W1[9][dim]*dist
//   c_q = b1 + pos_q·(W1[0:3]+W1[6:9])   (registers, computed at block init)
//   d_o = pos_o·(W1[3:6]-W1[6:9])        (computed during LDS chunk staging)
// Online softmax in log2 domain over o-chunks. SY>1: partials to ws.
// SY==1: normalize + write d_out directly (no workspace touched).
// LDS dim-group rotation g=(j+k)&7 keeps the 4 thread-slots of a query on
// distinct bank quads for every ds_read_b128.
// ---------------------------------------------------------------------------
__global__ __launch_bounds__(256, 2) void gano_main(
    const float* __restrict__ v,          // h_obs buffer, now holding v
    const float* __restrict__ pos_obs,
    const float* __restrict__ pos_query,
    const int* __restrict__ obs_batch,
    const int* __restrict__ query_batch,
    const float* __restrict__ W1,
    const float* __restrict__ b1,
    const float* __restrict__ W2,
    const float* __restrict__ b2,
    float* __restrict__ ws,
    float* __restrict__ out,
    int SY)
{
    __shared__ __align__(16) float ld[CHUNK*LAT];   // d_o tile
    __shared__ __align__(16) float lv[CHUNK*LAT];   // v tile
    __shared__ __align__(16) float lw2[LAT*4];      // W2 * log2e, [dim][head]
    __shared__ __align__(16) float w1d[3*LAT];      // W1[3+a]-W1[6+a]
    __shared__ float lpos[CHUNK*3];
    __shared__ int   lob[CHUNK];

    const int tid = threadIdx.x;
    const int k  = tid & 3;       // head / dim-slot
    const int qi = tid >> 2;      // query within block
    const int q  = blockIdx.x * 64 + qi;

    // --- per-block LDS constants (visible after first in-loop barrier) ---
    lw2[tid]       = W2[tid]       * LOG2E;
    lw2[tid + 256] = W2[tid + 256] * LOG2E;
    for (int i = tid; i < 3*LAT; i += 256) {
        const int a = i >> 7, dd = i & 127;
        w1d[i] = W1[(3+a)*LAT + dd] - W1[(6+a)*LAT + dd];
    }

    // --- per-thread constants ---
    const float pqx = pos_query[q*3+0];
    const float pqy = pos_query[q*3+1];
    const float pqz = pos_query[q*3+2];
    const int   qb  = query_batch[q];
    const float b2k = b2[k] * LOG2E;

    float4 cq[8], wd[8], acc[8];
#pragma unroll
    for (int j = 0; j < 8; ++j) {
        const int g4 = ((j + k) & 7) * 4;
        const int d0 = k*HD + g4;
        float4 c = *(const float4*)(b1 + d0);
        const float pq_[3] = {pqx, pqy, pqz};
#pragma unroll
        for (int a = 0; a < 3; ++a) {
            const float4 w0 = *(const float4*)(W1 + a*LAT + d0);
            const float4 w6 = *(const float4*)(W1 + (6+a)*LAT + d0);
            c.x = fmaf(pq_[a], w0.x + w6.x, c.x);
            c.y = fmaf(pq_[a], w0.y + w6.y, c.y);
            c.z = fmaf(pq_[a], w0.z + w6.z, c.z);
            c.w = fmaf(pq_[a], w0.w + w6.w, c.w);
        }
        cq[j] = c;
        wd[j] = *(const float4*)(W1 + 9*LAT + d0);
        acc[j] = make_float4(0.f, 0.f, 0.f, 0.f);
    }

    float m = NEG_BIG, lsum = 0.f;

    for (int cb = blockIdx.y; cb * CHUNK < NO; cb += SY) {
        const int o0 = cb * CHUNK;
        const int clen = (NO - o0 < CHUNK) ? (NO - o0) : CHUNK;
        __syncthreads();   // previous chunk fully consumed / constants ready
        {
            const int n4 = clen * (LAT/4);
            for (int i = tid; i < n4; i += 256) {
                const int oo = i >> 5;          // obs within chunk
                const int d4 = (i & 31) * 4;    // dim group
                const float* po = pos_obs + (size_t)(o0 + oo)*3;
                const float px = po[0], py = po[1], pz = po[2];
                const float4 wa = *(const float4*)(w1d + 0*LAT + d4);
                const float4 wb = *(const float4*)(w1d + 1*LAT + d4);
                const float4 wc = *(const float4*)(w1d + 2*LAT + d4);
                float4 r;
                r.x = fmaf(px, wa.x, fmaf(py, wb.x, pz*wc.x));
                r.y = fmaf(px, wa.y, fmaf(py, wb.y, pz*wc.y));
                r.z = fmaf(px, wa.z, fmaf(py, wb.z, pz*wc.z));
                r.w = fmaf(px, wa.w, fmaf(py, wb.w, pz*wc.w));
                *(float4*)(ld + oo*LAT + d4) = r;
                *(float4*)(lv + oo*LAT + d4) =
                    *(const float4*)(v + (size_t)(o0+oo)*LAT + d4);
            }
            for (int i = tid; i < clen*3; i += 256) lpos[i] = pos_obs[o0*3 + i];
            for (int i = tid; i < clen;   i += 256) lob[i]  = obs_batch[o0 + i];
        }
        __syncthreads();

#pragma unroll 1
        for (int oc = 0; oc < clen; ++oc) {
            const float dx = pqx - lpos[oc*3+0];
            const float dy = pqy - lpos[oc*3+1];
            const float dz = pqz - lpos[oc*3+2];
            const float dist = sqrtf(dx*dx + dy*dy + dz*dz);
            const int mb = (lob[oc] == qb);

            float lg0 = 0.f, lg1 = 0.f, lg2 = 0.f, lg3 = 0.f;
            const float* dbase = ld + oc*LAT + k*HD;
#pragma unroll
            for (int j = 0; j < 8; ++j) {
                const int g4 = ((j + k) & 7) * 4;
                const float4 d = *(const float4*)(dbase + g4);
                const float h0 = fmaxf(fmaf(wd[j].x, dist, cq[j].x + d.x), 0.f);
                const float h1 = fmaxf(fmaf(wd[j].y, dist, cq[j].y + d.y), 0.f);
                const float h2 = fmaxf(fmaf(wd[j].z, dist, cq[j].z + d.z), 0.f);
                const float h3 = fmaxf(fmaf(wd[j].w, dist, cq[j].w + d.w), 0.f);
                const int l4 = (k*HD + g4) * 4;
                const float4 wa = *(const float4*)(lw2 + l4);
                const float4 wb = *(const float4*)(lw2 + l4 + 4);
                const float4 wc = *(const float4*)(lw2 + l4 + 8);
                const float4 we = *(const float4*)(lw2 + l4 + 12);
                lg0 = fmaf(h0, wa.x, lg0); lg1 = fmaf(h0, wa.y, lg1);
                lg2 = fmaf(h0, wa.z, lg2); lg3 = fmaf(h0, wa.w, lg3);
                lg0 = fmaf(h1, wb.x, lg0); lg1 = fmaf(h1, wb.y, lg1);
                lg2 = fmaf(h1, wb.z, lg2); lg3 = fmaf(h1, wb.w, lg3);
                lg0 = fmaf(h2, wc.x, lg0); lg1 = fmaf(h2, wc.y, lg1);
                lg2 = fmaf(h2, wc.z, lg2); lg3 = fmaf(h2, wc.w, lg3);
                lg0 = fmaf(h3, we.x, lg0); lg1 = fmaf(h3, we.y, lg1);
                lg2 = fmaf(h3, we.z, lg2); lg3 = fmaf(h3, we.w, lg3);
            }
            // sum the 4 per-thread partial logits across the lane quad
            lg0 += __shfl_xor(lg0, 1); lg0 += __shfl_xor(lg0, 2);
            lg1 += __shfl_xor(lg1, 1); lg1 += __shfl_xor(lg1, 2);
            lg2 += __shfl_xor(lg2, 1); lg2 += __shfl_xor(lg2, 2);
            lg3 += __shfl_xor(lg3, 1); lg3 += __shfl_xor(lg3, 2);
            float logit = (k == 0) ? lg0 : ((k == 1) ? lg1 : ((k == 2) ? lg2 : lg3));
            logit += b2k;
            logit = mb ? logit : NEG_BIG;

            const float mn    = fmaxf(m, logit);
            const float alpha = exp2f(m - mn);
            const float p     = mb ? exp2f(logit - mn) : 0.f;
            lsum = fmaf(lsum, alpha, p);
            m = mn;

            const float* vbase = lv + oc*LAT + k*HD;
#pragma unroll
            for (int j = 0; j < 8; ++j) {
                const int g4 = ((j + k) & 7) * 4;
                const float4 vv = *(const float4*)(vbase + g4);
                acc[j].x = fmaf(acc[j].x, alpha, p*vv.x);
                acc[j].y = fmaf(acc[j].y, alpha, p*vv.y);
                acc[j].z = fmaf(acc[j].z, alpha, p*vv.z);
                acc[j].w = fmaf(acc[j].w, alpha, p*vv.w);
            }
        }
    }

    if (SY == 1) {
        const float inv = 1.0f / lsum;
        float* op = out + (size_t)q*LAT + k*HD;
#pragma unroll
        for (int j = 0; j < 8; ++j) {
            const int g4 = ((j + k) & 7) * 4;
            float4 r;
            r.x = acc[j].x * inv; r.y = acc[j].y * inv;
            r.z = acc[j].z * inv; r.w = acc[j].w * inv;
            *(float4*)(op + g4) = r;
        }
    } else {
        float* pp = ws + ((size_t)blockIdx.y * NQ + q) * PART_STRIDE;
        pp[k] = m;
        pp[4 + k] = lsum;
#pragma unroll
        for (int j = 0; j < 8; ++j) {
            const int g4 = ((j + k) & 7) * 4;
            *(float4*)(pp + 8 + k*HD + g4) = acc[j];
        }
    }
}

// ---------------------------------------------------------------------------
// combine: merge SY partials per query (log2-domain online merge), normalize
// ---------------------------------------------------------------------------
__global__ __launch_bounds__(128) void gano_combine(
    const float* __restrict__ ws, float* __restrict__ out, int SY)
{
    const int q = blockIdx.x;
    const int l = threadIdx.x;
    const int h = l >> 5;
    float M = NEG_BIG, Ls = 0.f, A = 0.f;
    for (int s = 0; s < SY; ++s) {
        const float* pp = ws + ((size_t)s * NQ + q) * PART_STRIDE;
        const float ms = pp[h];
        const float ls = pp[4 + h];
        const float as = pp[8 + l];
        const float Mn = fmaxf(M, ms);
        const float a0 = exp2f(M - Mn);
        const float a1 = exp2f(ms - Mn);
        Ls = Ls*a0 + ls*a1;
        A  = A *a0 + as*a1;
        M = Mn;
    }
    out[(size_t)q*LAT + l] = A / Ls;
}

// ---------------------------------------------------------------------------
extern "C" void kernel_launch(void* const* d_in, const int* in_sizes, int n_in,
                              void* d_out, int out_size, void* d_ws, size_t ws_size,
                              hipStream_t stream) {
    (void)in_sizes; (void)n_in; (void)out_size;
    float*       h_obs     = (float*)d_in[0];        // mutated in place -> v
    const float* pos_obs   = (const float*)d_in[1];
    const float* pos_query = (const float*)d_in[2];
    const int*   obs_batch = (const int*)d_in[3];
    const int*   query_batch = (const int*)d_in[4];
    const float* W1 = (const float*)d_in[5];
    const float* b1 = (const float*)d_in[6];
    const float* W2 = (const float*)d_in[7];
    const float* b2 = (const float*)d_in[8];
    const float* ln_g = (const float*)d_in[9];
    const float* ln_b = (const float*)d_in[10];
    const float* Wv = (const float*)d_in[11];
    const float* bv = (const float*)d_in[12];
    float* ws  = (float*)d_ws;
    float* out = (float*)d_out;

    // split-O factor, strictly bounded by what d_ws can hold (0 bytes @ SY=1)
    int SY = 1;
    const size_t per = (size_t)NQ * PART_STRIDE * sizeof(float);
    if (ws && ws_size >= 2*per) {
        size_t s = ws_size / per;
        SY = (int)(s < 37 ? s : 37);
    }

    gano_value<<<NO, 128, 0, stream>>>(ln_g, ln_b, Wv, bv, h_obs);
    gano_main<<<dim3(NQ/64, SY), 256, 0, stream>>>(h_obs, pos_obs, pos_query,
                                                   obs_batch, query_batch,
                                                   W1, b1, W2, b2, ws, out, SY);
    if (SY > 1)
        gano_combine<<<NQ, 128, 0, stream>>>(ws, out, SY);
}